// Round 10
// baseline (309.534 us; speedup 1.0000x reference)
//
#include <hip/hip_runtime.h>

typedef float  f32x4 __attribute__((ext_vector_type(4)));
typedef short  s16x8 __attribute__((ext_vector_type(8)));

#define PK   256   // panel K-span (floats); 1KB burst per row
#define PSTR 260   // padded LDS row stride (2-way bank alias = free)
#define TM   32    // output rows per block

typedef const __attribute__((address_space(1))) float* gas1f;
typedef __attribute__((address_space(3))) float*       las3f;

__device__ __forceinline__ short f2bf(float f) {
  unsigned u = __builtin_bit_cast(unsigned, f);
  u += 0x7FFFu + ((u >> 16) & 1u);   // round-to-nearest-even
  return (short)(u >> 16);
}

// ---------------------------------------------------------------------------
// Kernel 1: Y^T build.  Yt[c][k] = bf16( sum_d x[k][d] * W[d][c] )
// LDS-transposed epilogue: Yt written as 512B contiguous runs.
// Kpad multiple of 256, zero-filled.  Offsets (elements):
//  v2v 0 (Kpad 6144) | v2e 196608 | e2e 393216 (Kpad 12032) | e2f 778240
//  f2f 1163264 (Kpad 8192); total 1425408 elems = 2.85 MB.
// ---------------------------------------------------------------------------
__global__ __launch_bounds__(256) void build_yt(
    const float* __restrict__ xv, const float* __restrict__ xe,
    const float* __restrict__ xf,
    const float* __restrict__ Wv2v, const float* __restrict__ Wv2e,
    const float* __restrict__ We2e, const float* __restrict__ We2f,
    const float* __restrict__ Wf2f, short* __restrict__ Yt)
{
  int bid = blockIdx.x;
  const float* x; const float* W; int K, Kpad; size_t yoff;
  if (bid < 24)       { x=xv; W=Wv2v; K=6000;  Kpad=6144;  yoff=0;       }
  else if (bid < 48)  { x=xv; W=Wv2e; K=6000;  Kpad=6144;  yoff=196608;  bid-=24; }
  else if (bid < 95)  { x=xe; W=We2e; K=12000; Kpad=12032; yoff=393216;  bid-=48; }
  else if (bid < 142) { x=xe; W=We2f; K=12000; Kpad=12032; yoff=778240;  bid-=95; }
  else                { x=xf; W=Wf2f; K=8000;  Kpad=8192;  yoff=1163264; bid-=142; }

  __shared__ float Wl[32][32];
  __shared__ short sh[32][264];        // 264: 16B-aligned rows, bank-spread
  int tid = threadIdx.x;
  #pragma unroll
  for (int i = 0; i < 4; ++i) {
    int e = tid + i * 256;
    Wl[e >> 5][e & 31] = W[e];
  }
  __syncthreads();

  int row = bid * 256 + tid;           // always < Kpad
  float acc[32];
  #pragma unroll
  for (int c = 0; c < 32; ++c) acc[c] = 0.f;

  if (row < K) {
    const float* xp = x + (size_t)row * 32;
    float xr[32];
    #pragma unroll
    for (int i = 0; i < 8; ++i) {
      f32x4 v = *(const f32x4*)(xp + i * 4);
      xr[i*4+0] = v.x; xr[i*4+1] = v.y; xr[i*4+2] = v.z; xr[i*4+3] = v.w;
    }
    #pragma unroll
    for (int d = 0; d < 32; ++d) {
      float xd = xr[d];
      #pragma unroll
      for (int c = 0; c < 32; ++c) acc[c] += xd * Wl[d][c];
    }
  }
  #pragma unroll
  for (int c = 0; c < 32; ++c) sh[c][tid] = f2bf(acc[c]);
  __syncthreads();

  // coalesced store: 8 threads per Yt row; each thread 32 shorts (64B)
  int c = tid >> 3, q = tid & 7;
  const short* sp = &sh[c][q * 32];
  short* dp = Yt + yoff + (size_t)c * Kpad + (size_t)bid * 256 + q * 32;
  #pragma unroll
  for (int i = 0; i < 4; ++i)
    *(s16x8*)(dp + i * 8) = *(const s16x8*)(sp + i * 8);
}

// ---------------------------------------------------------------------------
// Kernel 2: skinny GEMM, TM=32, 3 chunks/tile (23-27 panels each) for tail
// smoothing. 512 threads / 8 waves; counted-vmcnt pipeline per chunk.
// ---------------------------------------------------------------------------
__device__ __forceinline__ void stage_panel(
    const float* __restrict__ G, int K, int row0, int pn, int lane, int w,
    float (*panel)[TM][PSTR], int bb)
{
  if ((pn + 1) * PK <= K) {            // full panel: 1KB DMA burst per row
    const float* base = G + (size_t)row0 * K + (size_t)pn * PK;
    #pragma unroll
    for (int j = 0; j < 4; ++j) {
      int rr = 4 * w + j;              // 8 waves x 4 rows = 32
      __builtin_amdgcn_global_load_lds((gas1f)(base + (size_t)rr * K + lane * 4),
                                       (las3f)&panel[bb][rr][0], 16, 0, 2 /*nt*/);
    }
  } else {                             // tail: reg-staged, masked, zero-filled
    #pragma unroll
    for (int j = 0; j < 4; ++j) {
      int rr = 4 * w + j;
      int k = pn * PK + lane * 4;
      f32x4 v = {0.f, 0.f, 0.f, 0.f};
      if (k < K) v = *(const f32x4*)(G + (size_t)(row0 + rr) * K + k);
      *(f32x4*)&panel[bb][rr][lane * 4] = v;
    }
  }
}

__device__ __forceinline__ void loadB(const short* __restrict__ Y, int Kp,
                                      int r, int g, int w, int p, s16x8 B[2])
{
  int kg = p * PK + w * 32 + g * 8;    // wave w owns k-step w of the panel
  B[0] = *(const s16x8*)(Y + (size_t)r        * Kp + kg);
  B[1] = *(const s16x8*)(Y + (size_t)(r + 16) * Kp + kg);
}

__device__ __forceinline__ void seg_run(
    const float* __restrict__ G, const short* __restrict__ Yt,
    int K, int Kp, int row0, int p_lo, int p_hi, int lane, int w,
    float (*panel)[TM][PSTR],
    f32x4& acc00, f32x4& acc01, f32x4& acc10, f32x4& acc11)
{
  if (p_lo >= p_hi) return;
  int r = lane & 15, g = lane >> 4;
  s16x8 Bc[2], Bn[2];

  // prologue, per-wave FIFO: stage(p_lo)[4] < B(p_lo)[2] < stage(p_lo+1)[4]
  stage_panel(G, K, row0, p_lo, lane, w, panel, p_lo & 1);
  loadB(Yt, Kp, r, g, w, p_lo, Bc);
  if (p_lo + 1 < p_hi) stage_panel(G, K, row0, p_lo + 1, lane, w, panel, (p_lo + 1) & 1);

  for (int p = p_lo; p < p_hi; ++p) {
    // wait: stage(p)+B(p) done; stage(p+1) (if DMA-staged) stays in flight
    if (p + 1 < p_hi && (p + 2) * PK <= K)
      asm volatile("s_waitcnt vmcnt(4)" ::: "memory");
    else
      asm volatile("s_waitcnt vmcnt(0)" ::: "memory");
    __builtin_amdgcn_s_barrier();

    int b  = p & 1;
    int kk = w * 32 + g * 8;
    f32x4 l0 = *(const f32x4*)&panel[b][r][kk];
    f32x4 l1 = *(const f32x4*)&panel[b][r][kk + 4];
    f32x4 h0 = *(const f32x4*)&panel[b][r + 16][kk];
    f32x4 h1 = *(const f32x4*)&panel[b][r + 16][kk + 4];
    s16x8 alo, ahi;
    alo[0]=f2bf(l0.x); alo[1]=f2bf(l0.y); alo[2]=f2bf(l0.z); alo[3]=f2bf(l0.w);
    alo[4]=f2bf(l1.x); alo[5]=f2bf(l1.y); alo[6]=f2bf(l1.z); alo[7]=f2bf(l1.w);
    ahi[0]=f2bf(h0.x); ahi[1]=f2bf(h0.y); ahi[2]=f2bf(h0.z); ahi[3]=f2bf(h0.w);
    ahi[4]=f2bf(h1.x); ahi[5]=f2bf(h1.y); ahi[6]=f2bf(h1.z); ahi[7]=f2bf(h1.w);
    acc00 = __builtin_amdgcn_mfma_f32_16x16x32_bf16(alo, Bc[0], acc00, 0, 0, 0);
    acc01 = __builtin_amdgcn_mfma_f32_16x16x32_bf16(alo, Bc[1], acc01, 0, 0, 0);
    acc10 = __builtin_amdgcn_mfma_f32_16x16x32_bf16(ahi, Bc[0], acc10, 0, 0, 0);
    acc11 = __builtin_amdgcn_mfma_f32_16x16x32_bf16(ahi, Bc[1], acc11, 0, 0, 0);

    bool have_next = (p + 1 < p_hi);
    if (have_next) loadB(Yt, Kp, r, g, w, p + 1, Bn);   // flies across barrier

    asm volatile("s_waitcnt lgkmcnt(0)" ::: "memory");
    __builtin_amdgcn_sched_barrier(0);
    __builtin_amdgcn_s_barrier();      // all waves done reading buf b
    if (p + 2 < p_hi) stage_panel(G, K, row0, p + 2, lane, w, panel, b);

    if (have_next) { Bc[0] = Bn[0]; Bc[1] = Bn[1]; }
  }
  __syncthreads();                     // chunk epilogue: full drain
}

// grid = 2063 (3 chunks per zf/ze tile, 1 per zv tile), heavy-first:
//  [0,750)     zf: tile=bid/3, c=bid%3
//    c0 Ge2f[0,27)            -> out     c1 Ge2f[27,47)+Gf2f[0,6) -> part 2t
//    c2 Gf2f[6,32)            -> part 2t+1
//  [750,1875)  ze: tile=(bid-750)/3, c=(bid-750)%3
//    c0 Gv2e[0,24)            -> out     c1 Ge2e[0,24)  -> part 500+2t
//    c2 Ge2e[24,47)           -> part 500+2t+1
//  [1875,2063) zv: Gv2v[0,24) -> out  (last tile overlaps rows 5968-5999)
__global__ __launch_bounds__(512) void gemm_skinny(
    const float* __restrict__ Gv2v, const float* __restrict__ Gv2e,
    const float* __restrict__ Ge2e, const float* __restrict__ Ge2f,
    const float* __restrict__ Gf2f, const short* __restrict__ Yt,
    float* __restrict__ part, float* __restrict__ out)
{
  __shared__ float panel[2][TM][PSTR];   // 66,560 B; reused for reduce

  int bid  = blockIdx.x;
  int lane = threadIdx.x & 63, w = threadIdx.x >> 6;

  const float *Ga, *Gb = nullptr; const short *Ya, *Yb = nullptr;
  int Ka, Kpa, alo, ahi, Kb = 0, Kpb = 0, blo = 0, bhi = 0, tile, row0;
  float* dst;
  if (bid < 750) {                     // zf
    tile = bid / 3; int c = bid - tile * 3; row0 = tile * TM;
    if (c == 0) {
      Ga = Ge2f; Ya = Yt + 778240; Ka = 12000; Kpa = 12032; alo = 0;  ahi = 27;
      dst = out + 576000 + (size_t)tile * 1024;
    } else if (c == 1) {
      Ga = Ge2f; Ya = Yt + 778240;  Ka = 12000; Kpa = 12032; alo = 27; ahi = 47;
      Gb = Gf2f; Yb = Yt + 1163264; Kb = 8000;  Kpb = 8192;  blo = 0;  bhi = 6;
      dst = part + (size_t)(tile * 2) * 1024;
    } else {
      Ga = Gf2f; Ya = Yt + 1163264; Ka = 8000; Kpa = 8192; alo = 6; ahi = 32;
      dst = part + (size_t)(tile * 2 + 1) * 1024;
    }
  } else if (bid < 1875) {             // ze
    int t2 = bid - 750; tile = t2 / 3; int c = t2 - tile * 3; row0 = tile * TM;
    if (c == 0) {
      Ga = Gv2e; Ya = Yt + 196608; Ka = 6000; Kpa = 6144; alo = 0; ahi = 24;
      dst = out + 192000 + (size_t)tile * 1024;
    } else if (c == 1) {
      Ga = Ge2e; Ya = Yt + 393216; Ka = 12000; Kpa = 12032; alo = 0; ahi = 24;
      dst = part + (size_t)(500 + tile * 2) * 1024;
    } else {
      Ga = Ge2e; Ya = Yt + 393216; Ka = 12000; Kpa = 12032; alo = 24; ahi = 47;
      dst = part + (size_t)(500 + tile * 2 + 1) * 1024;
    }
  } else {                             // zv
    tile = bid - 1875; row0 = tile * TM;
    if (row0 + TM > 6000) row0 = 6000 - TM;   // overlap tile (same values)
    Ga = Gv2v; Ya = Yt; Ka = 6000; Kpa = 6144; alo = 0; ahi = 24;
    dst = out + (size_t)row0 * 32;
  }

  f32x4 acc00 = {0.f,0.f,0.f,0.f}, acc01 = {0.f,0.f,0.f,0.f};
  f32x4 acc10 = {0.f,0.f,0.f,0.f}, acc11 = {0.f,0.f,0.f,0.f};
  seg_run(Ga, Ya, Ka, Kpa, row0, alo, ahi, lane, w, panel,
          acc00, acc01, acc10, acc11);
  if (Gb)
    seg_run(Gb, Yb, Kb, Kpb, row0, blo, bhi, lane, w, panel,
            acc00, acc01, acc10, acc11);

  // cross-wave reduce (C/D layout: col = lane&15, row = (lane>>4)*4+reg)
  float (*red)[1024] = (float (*)[1024])panel;   // 8x1024 f, aliases panel
  int r = lane & 15, g = lane >> 4;
  #pragma unroll
  for (int q = 0; q < 4; ++q) {
    int rl = g * 4 + q;
    red[w][ rl       * 32 +      r] = acc00[q];
    red[w][ rl       * 32 + 16 + r] = acc01[q];
    red[w][(rl + 16) * 32 +      r] = acc10[q];
    red[w][(rl + 16) * 32 + 16 + r] = acc11[q];
  }
  __syncthreads();
  #pragma unroll
  for (int i = 0; i < 2; ++i) {
    int e = (int)threadIdx.x + i * 512;
    float s = red[0][e] + red[1][e] + red[2][e] + red[3][e]
            + red[4][e] + red[5][e] + red[6][e] + red[7][e];
    dst[e] = s;
  }
}

// out += sum of 2 partials per tile.  zf tiles 0..249, ze tiles 0..374.
__global__ __launch_bounds__(256) void reduce_partials(
    float* __restrict__ out, const float* __restrict__ part)
{
  int e = blockIdx.x * 256 + threadIdx.x;     // grid 2500 -> 640000
  if (e < 256000) {                           // zf: 250 tiles x 1024
    int t = e >> 10, wi = e & 1023;
    const float* p = part + (size_t)(t * 2) * 1024;
    out[576000 + e] += p[wi] + p[1024 + wi];
  } else {                                    // ze: 375 tiles x 1024
    int e2 = e - 256000;
    int t = e2 >> 10, wi = e2 & 1023;
    const float* p = part + (size_t)(500 + t * 2) * 1024;
    out[192000 + e2] += p[wi] + p[1024 + wi];
  }
}

extern "C" void kernel_launch(void* const* d_in, const int* in_sizes, int n_in,
                              void* d_out, int out_size, void* d_ws, size_t ws_size,
                              hipStream_t stream) {
  const float* xv   = (const float*)d_in[0];
  const float* xe   = (const float*)d_in[1];
  const float* xf   = (const float*)d_in[2];
  const float* Gv2v = (const float*)d_in[3];
  const float* Gv2e = (const float*)d_in[4];
  const float* Ge2e = (const float*)d_in[5];
  const float* Ge2f = (const float*)d_in[6];
  const float* Gf2f = (const float*)d_in[7];
  const float* Wv2v = (const float*)d_in[8];
  const float* Wv2e = (const float*)d_in[9];
  const float* We2e = (const float*)d_in[10];
  const float* We2f = (const float*)d_in[11];
  const float* Wf2f = (const float*)d_in[12];
  short* Yt   = (short*)d_ws;
  float* part = (float*)((char*)d_ws + 2850816);   // 1250 x 1024 f32 = 5.12 MB
  float* out  = (float*)d_out;

  hipLaunchKernelGGL(build_yt, dim3(174), dim3(256), 0, stream,
                     xv, xe, xf, Wv2v, Wv2e, We2e, We2f, Wf2f, Yt);
  hipLaunchKernelGGL(gemm_skinny, dim3(2063), dim3(512), 0, stream,
                     Gv2v, Gv2e, Ge2e, Ge2f, Gf2f, Yt, part, out);
  hipLaunchKernelGGL(reduce_partials, dim3(2500), dim3(256), 0, stream,
                     out, part);
}

// Round 11
// 295.383 us; speedup vs baseline: 1.0479x; 1.0479x over previous
//
#include <hip/hip_runtime.h>

typedef float  f32x4 __attribute__((ext_vector_type(4)));
typedef short  s16x8 __attribute__((ext_vector_type(8)));

#define PK   256   // panel K-span (floats); 1KB burst per row
#define PSTR 260   // padded LDS row stride (2-way bank alias = free)
#define TM   32    // output rows per block

typedef const __attribute__((address_space(1))) float* gas1f;
typedef __attribute__((address_space(3))) float*       las3f;

__device__ __forceinline__ short f2bf(float f) {
  unsigned u = __builtin_bit_cast(unsigned, f);
  u += 0x7FFFu + ((u >> 16) & 1u);   // round-to-nearest-even
  return (short)(u >> 16);
}

// ---------------------------------------------------------------------------
// Kernel 1: Y^T build.  Yt[c][k] = bf16( sum_d x[k][d] * W[d][c] )
// LDS-transposed epilogue: Yt written as 512B contiguous runs.
// Kpad multiple of 256, zero-filled.  Offsets (elements):
//  v2v 0 (Kpad 6144) | v2e 196608 | e2e 393216 (Kpad 12032) | e2f 778240
//  f2f 1163264 (Kpad 8192); total 1425408 elems = 2.85 MB.
// ---------------------------------------------------------------------------
__global__ __launch_bounds__(256) void build_yt(
    const float* __restrict__ xv, const float* __restrict__ xe,
    const float* __restrict__ xf,
    const float* __restrict__ Wv2v, const float* __restrict__ Wv2e,
    const float* __restrict__ We2e, const float* __restrict__ We2f,
    const float* __restrict__ Wf2f, short* __restrict__ Yt)
{
  int bid = blockIdx.x;
  const float* x; const float* W; int K, Kpad; size_t yoff;
  if (bid < 24)       { x=xv; W=Wv2v; K=6000;  Kpad=6144;  yoff=0;       }
  else if (bid < 48)  { x=xv; W=Wv2e; K=6000;  Kpad=6144;  yoff=196608;  bid-=24; }
  else if (bid < 95)  { x=xe; W=We2e; K=12000; Kpad=12032; yoff=393216;  bid-=48; }
  else if (bid < 142) { x=xe; W=We2f; K=12000; Kpad=12032; yoff=778240;  bid-=95; }
  else                { x=xf; W=Wf2f; K=8000;  Kpad=8192;  yoff=1163264; bid-=142; }

  __shared__ float Wl[32][32];
  __shared__ short sh[32][264];        // 264: 16B-aligned rows, bank-spread
  int tid = threadIdx.x;
  #pragma unroll
  for (int i = 0; i < 4; ++i) {
    int e = tid + i * 256;
    Wl[e >> 5][e & 31] = W[e];
  }
  __syncthreads();

  int row = bid * 256 + tid;           // always < Kpad
  float acc[32];
  #pragma unroll
  for (int c = 0; c < 32; ++c) acc[c] = 0.f;

  if (row < K) {
    const float* xp = x + (size_t)row * 32;
    float xr[32];
    #pragma unroll
    for (int i = 0; i < 8; ++i) {
      f32x4 v = *(const f32x4*)(xp + i * 4);
      xr[i*4+0] = v.x; xr[i*4+1] = v.y; xr[i*4+2] = v.z; xr[i*4+3] = v.w;
    }
    #pragma unroll
    for (int d = 0; d < 32; ++d) {
      float xd = xr[d];
      #pragma unroll
      for (int c = 0; c < 32; ++c) acc[c] += xd * Wl[d][c];
    }
  }
  #pragma unroll
  for (int c = 0; c < 32; ++c) sh[c][tid] = f2bf(acc[c]);
  __syncthreads();

  // coalesced store: 8 threads per Yt row; each thread 32 shorts (64B)
  int c = tid >> 3, q = tid & 7;
  const short* sp = &sh[c][q * 32];
  short* dp = Yt + yoff + (size_t)c * Kpad + (size_t)bid * 256 + q * 32;
  #pragma unroll
  for (int i = 0; i < 4; ++i)
    *(s16x8*)(dp + i * 8) = *(const s16x8*)(sp + i * 8);
}

// ---------------------------------------------------------------------------
// Kernel 2: skinny GEMM, TM=32, K-chunked (2 chunks/tile) for tail smoothing.
// 512 threads / 8 waves; counted-vmcnt pipeline preserved per chunk.
// Chunk A writes out directly; chunk B writes one fp32 partial per tile.
// ---------------------------------------------------------------------------
__device__ __forceinline__ void stage_panel(
    const float* __restrict__ G, int K, int row0, int pn, int lane, int w,
    float (*panel)[TM][PSTR], int bb)
{
  if ((pn + 1) * PK <= K) {            // full panel: 1KB DMA burst per row
    const float* base = G + (size_t)row0 * K + (size_t)pn * PK;
    #pragma unroll
    for (int j = 0; j < 4; ++j) {
      int rr = 4 * w + j;              // 8 waves x 4 rows = 32
      __builtin_amdgcn_global_load_lds((gas1f)(base + (size_t)rr * K + lane * 4),
                                       (las3f)&panel[bb][rr][0], 16, 0, 2 /*nt*/);
    }
  } else {                             // tail: reg-staged, masked, zero-filled
    #pragma unroll
    for (int j = 0; j < 4; ++j) {
      int rr = 4 * w + j;
      int k = pn * PK + lane * 4;
      f32x4 v = {0.f, 0.f, 0.f, 0.f};
      if (k < K) v = *(const f32x4*)(G + (size_t)(row0 + rr) * K + k);
      *(f32x4*)&panel[bb][rr][lane * 4] = v;
    }
  }
}

__device__ __forceinline__ void loadB(const short* __restrict__ Y, int Kp,
                                      int r, int g, int w, int p, s16x8 B[2])
{
  int kg = p * PK + w * 32 + g * 8;    // wave w owns k-step w of the panel
  B[0] = *(const s16x8*)(Y + (size_t)r        * Kp + kg);
  B[1] = *(const s16x8*)(Y + (size_t)(r + 16) * Kp + kg);
}

__device__ __forceinline__ void seg_run(
    const float* __restrict__ G, const short* __restrict__ Yt,
    int K, int Kp, int row0, int p_lo, int p_hi, int lane, int w,
    float (*panel)[TM][PSTR],
    f32x4& acc00, f32x4& acc01, f32x4& acc10, f32x4& acc11)
{
  if (p_lo >= p_hi) return;
  int r = lane & 15, g = lane >> 4;
  s16x8 Bc[2], Bn[2];

  // prologue, per-wave FIFO: stage(p_lo)[4] < B(p_lo)[2] < stage(p_lo+1)[4]
  stage_panel(G, K, row0, p_lo, lane, w, panel, p_lo & 1);
  loadB(Yt, Kp, r, g, w, p_lo, Bc);
  if (p_lo + 1 < p_hi) stage_panel(G, K, row0, p_lo + 1, lane, w, panel, (p_lo + 1) & 1);

  for (int p = p_lo; p < p_hi; ++p) {
    // wait: stage(p)+B(p) done; stage(p+1) (if DMA-staged) stays in flight
    if (p + 1 < p_hi && (p + 2) * PK <= K)
      asm volatile("s_waitcnt vmcnt(4)" ::: "memory");
    else
      asm volatile("s_waitcnt vmcnt(0)" ::: "memory");
    __builtin_amdgcn_s_barrier();

    int b  = p & 1;
    int kk = w * 32 + g * 8;
    f32x4 l0 = *(const f32x4*)&panel[b][r][kk];
    f32x4 l1 = *(const f32x4*)&panel[b][r][kk + 4];
    f32x4 h0 = *(const f32x4*)&panel[b][r + 16][kk];
    f32x4 h1 = *(const f32x4*)&panel[b][r + 16][kk + 4];
    s16x8 alo, ahi;
    alo[0]=f2bf(l0.x); alo[1]=f2bf(l0.y); alo[2]=f2bf(l0.z); alo[3]=f2bf(l0.w);
    alo[4]=f2bf(l1.x); alo[5]=f2bf(l1.y); alo[6]=f2bf(l1.z); alo[7]=f2bf(l1.w);
    ahi[0]=f2bf(h0.x); ahi[1]=f2bf(h0.y); ahi[2]=f2bf(h0.z); ahi[3]=f2bf(h0.w);
    ahi[4]=f2bf(h1.x); ahi[5]=f2bf(h1.y); ahi[6]=f2bf(h1.z); ahi[7]=f2bf(h1.w);
    acc00 = __builtin_amdgcn_mfma_f32_16x16x32_bf16(alo, Bc[0], acc00, 0, 0, 0);
    acc01 = __builtin_amdgcn_mfma_f32_16x16x32_bf16(alo, Bc[1], acc01, 0, 0, 0);
    acc10 = __builtin_amdgcn_mfma_f32_16x16x32_bf16(ahi, Bc[0], acc10, 0, 0, 0);
    acc11 = __builtin_amdgcn_mfma_f32_16x16x32_bf16(ahi, Bc[1], acc11, 0, 0, 0);

    bool have_next = (p + 1 < p_hi);
    if (have_next) loadB(Yt, Kp, r, g, w, p + 1, Bn);   // flies across barrier

    asm volatile("s_waitcnt lgkmcnt(0)" ::: "memory");
    __builtin_amdgcn_sched_barrier(0);
    __builtin_amdgcn_s_barrier();      // all waves done reading buf b
    if (p + 2 < p_hi) stage_panel(G, K, row0, p + 2, lane, w, panel, b);

    if (have_next) { Bc[0] = Bn[0]; Bc[1] = Bn[1]; }
  }
  __syncthreads();                     // chunk epilogue: full drain
}

// grid = 1438:
//  [0,250)    zfA: Ge2f[0,40)                 -> out   (tile = bid)
//  [250,500)  zfB: Ge2f[40,47)+Gf2f[0,32)     -> part[tile]
//  [500,875)  zeB: Ge2e[11,47)                -> part[250+tile]
//  [875,1250) zeA: Gv2e[0,24)+Ge2e[0,11)      -> out
//  [1250,1438) zv: Gv2v[0,24)                 -> out
__global__ __launch_bounds__(512) void gemm_skinny(
    const float* __restrict__ Gv2v, const float* __restrict__ Gv2e,
    const float* __restrict__ Ge2e, const float* __restrict__ Ge2f,
    const float* __restrict__ Gf2f, const short* __restrict__ Yt,
    float* __restrict__ part, float* __restrict__ out)
{
  __shared__ float panel[2][TM][PSTR];   // 66,560 B; reused for reduce

  int bid  = blockIdx.x;
  int lane = threadIdx.x & 63, w = threadIdx.x >> 6;

  const float *Ga, *Gb = nullptr; const short *Ya, *Yb = nullptr;
  int Ka, Kpa, alo, ahi, Kb = 0, Kpb = 0, blo = 0, bhi = 0, tile, row0;
  float* dst;
  if (bid < 250) {                     // zfA (direct)
    tile = bid; row0 = tile * TM;
    Ga = Ge2f; Ya = Yt + 778240; Ka = 12000; Kpa = 12032; alo = 0;  ahi = 40;
    dst = out + 576000 + (size_t)tile * 1024;
  } else if (bid < 500) {              // zfB (partial)
    tile = bid - 250; row0 = tile * TM;
    Ga = Ge2f; Ya = Yt + 778240;  Ka = 12000; Kpa = 12032; alo = 40; ahi = 47;
    Gb = Gf2f; Yb = Yt + 1163264; Kb = 8000;  Kpb = 8192;  blo = 0;  bhi = 32;
    dst = part + (size_t)tile * 1024;
  } else if (bid < 875) {              // zeB (partial)
    tile = bid - 500; row0 = tile * TM;
    Ga = Ge2e; Ya = Yt + 393216; Ka = 12000; Kpa = 12032; alo = 11; ahi = 47;
    dst = part + (size_t)(250 + tile) * 1024;
  } else if (bid < 1250) {             // zeA (direct)
    tile = bid - 875; row0 = tile * TM;
    Ga = Gv2e; Ya = Yt + 196608; Ka = 6000;  Kpa = 6144;  alo = 0; ahi = 24;
    Gb = Ge2e; Yb = Yt + 393216; Kb = 12000; Kpb = 12032; blo = 0; bhi = 11;
    dst = out + 192000 + (size_t)tile * 1024;
  } else {                             // zv (direct)
    tile = bid - 1250; row0 = tile * TM;
    if (row0 + TM > 6000) row0 = 6000 - TM;   // overlap tile (same values)
    Ga = Gv2v; Ya = Yt; Ka = 6000; Kpa = 6144; alo = 0; ahi = 24;
    dst = out + (size_t)row0 * 32;
  }

  f32x4 acc00 = {0.f,0.f,0.f,0.f}, acc01 = {0.f,0.f,0.f,0.f};
  f32x4 acc10 = {0.f,0.f,0.f,0.f}, acc11 = {0.f,0.f,0.f,0.f};
  seg_run(Ga, Ya, Ka, Kpa, row0, alo, ahi, lane, w, panel,
          acc00, acc01, acc10, acc11);
  if (Gb)
    seg_run(Gb, Yb, Kb, Kpb, row0, blo, bhi, lane, w, panel,
            acc00, acc01, acc10, acc11);

  // cross-wave reduce (C/D layout: col = lane&15, row = (lane>>4)*4+reg)
  float (*red)[1024] = (float (*)[1024])panel;   // 8x1024 f, aliases panel
  int r = lane & 15, g = lane >> 4;
  #pragma unroll
  for (int q = 0; q < 4; ++q) {
    int rl = g * 4 + q;
    red[w][ rl       * 32 +      r] = acc00[q];
    red[w][ rl       * 32 + 16 + r] = acc01[q];
    red[w][(rl + 16) * 32 +      r] = acc10[q];
    red[w][(rl + 16) * 32 + 16 + r] = acc11[q];
  }
  __syncthreads();
  #pragma unroll
  for (int i = 0; i < 2; ++i) {
    int e = (int)threadIdx.x + i * 512;
    float s = red[0][e] + red[1][e] + red[2][e] + red[3][e]
            + red[4][e] + red[5][e] + red[6][e] + red[7][e];
    dst[e] = s;
  }
}

// out += part.  zf: 250 tiles (out+576000); ze: 375 tiles (out+192000).
__global__ __launch_bounds__(256) void reduce_partials(
    float* __restrict__ out, const float* __restrict__ part)
{
  int e = blockIdx.x * 256 + threadIdx.x;     // grid 2500 -> 640000
  if (e < 256000) {
    out[576000 + e] += part[e];
  } else {
    int e2 = e - 256000;                      // < 384000
    out[192000 + e2] += part[256000 + e2];
  }
}

extern "C" void kernel_launch(void* const* d_in, const int* in_sizes, int n_in,
                              void* d_out, int out_size, void* d_ws, size_t ws_size,
                              hipStream_t stream) {
  const float* xv   = (const float*)d_in[0];
  const float* xe   = (const float*)d_in[1];
  const float* xf   = (const float*)d_in[2];
  const float* Gv2v = (const float*)d_in[3];
  const float* Gv2e = (const float*)d_in[4];
  const float* Ge2e = (const float*)d_in[5];
  const float* Ge2f = (const float*)d_in[6];
  const float* Gf2f = (const float*)d_in[7];
  const float* Wv2v = (const float*)d_in[8];
  const float* Wv2e = (const float*)d_in[9];
  const float* We2e = (const float*)d_in[10];
  const float* We2f = (const float*)d_in[11];
  const float* Wf2f = (const float*)d_in[12];
  short* Yt   = (short*)d_ws;
  float* part = (float*)((char*)d_ws + 2850816);   // 625 x 1024 f32 = 2.56 MB
  float* out  = (float*)d_out;

  hipLaunchKernelGGL(build_yt, dim3(174), dim3(256), 0, stream,
                     xv, xe, xf, Wv2v, Wv2e, We2e, We2f, Wf2f, Yt);
  hipLaunchKernelGGL(gemm_skinny, dim3(1438), dim3(512), 0, stream,
                     Gv2v, Gv2e, Ge2e, Ge2f, Gf2f, Yt, part, out);
  hipLaunchKernelGGL(reduce_partials, dim3(2500), dim3(256), 0, stream,
                     out, part);
}